// Round 3
// baseline (264.323 us; speedup 1.0000x reference)
//
#include <hip/hip_runtime.h>

// out[n,m,:] = normalize(emb[m, g, :]),  g = gene_seq[n,m]
// N=256, M=2000, D=128. Output 262 MB fp32; write floor ~41 us at the
// 6.4 TB/s the harness fill kernels demonstrate with plain stores.
//
// R6 theory: R5 (register-held rows, n-loop) left ~2x over the write floor.
// Remaining structural deltas vs the 6.4 TB/s fill: 1 KB write bursts at
// 1 MB stride per wave, and a shfl+cndmask chain between stores. R6 stages a
// 32-gene tile of NORMALIZED rows in LDS (64 KB; LDS is immune to the write
// stream's L2 eviction) + the 32x32 gene-code slab (4 KB, m-contiguous rows
// of gene_seq), then streams n: per n the block writes a CONTIGUOUS 16 KB
// segment out[n, m0:m0+32, :] -- per store instruction each wave writes 1 KB
// contiguous, no cross-lane ops, 8 stores in flight per thread.
// Reads: 4 MB emb x8 n-chunk redundancy = 32 MB (+2 MB gene_seq) -- ~5 us.
// If this lands ~210-220 total, burst locality was the gap; if it stays
// ~257, the kernel was already at the write roofline and the residual is
// fixed harness cost (=> ROOFLINE next round).

#define N_SEQ   256
#define M_GENES 2000
#define D_DIM   128
#define TILE_M  32
#define N_TILES 63            // ceil(2000/32); tile 62 holds 16 genes
#define N_CHUNK 32
#define NCH     (N_SEQ / N_CHUNK)   // 8 -> grid 63 x 8 = 504 blocks
#define THREADS 512

typedef float vfloat4 __attribute__((ext_vector_type(4)));

__global__ __launch_bounds__(THREADS) void gene_embed_kernel(
    const int*   __restrict__ gene_seq,   // (N,M)
    const float* __restrict__ emb,        // (M,4,D)
    float*       __restrict__ out)        // (N,M,D)
{
    __shared__ float rowsN[TILE_M * 4 * D_DIM];   // 64 KB normalized rows
    __shared__ int   gtab[N_CHUNK * TILE_M];      // 4 KB gene codes

    const int tile = blockIdx.x;
    const int m0   = tile * TILE_M;
    const int mv   = min(TILE_M, M_GENES - m0);   // 32, or 16 on tile 62
    const int n0   = blockIdx.y * N_CHUNK;

    const int t    = threadIdx.x;
    const int w    = t >> 6;                      // wave 0..7
    const int lane = t & 63;
    const int c    = lane & 31;                   // float4 index in a row
    const int half = lane >> 5;

    // ---- Stage + normalize rows: 128 rows (mv*4), 2 rows per wave-iter ----
    {
        const float* embT = emb + (size_t)m0 * 4 * D_DIM;  // contiguous 64 KB slice
        const int R = mv * 4;
        #pragma unroll
        for (int it = 0; it < (TILE_M * 4) / 16; ++it) {   // 8 iters
            const int r = it * 16 + (w << 1) + half;       // row in tile
            if (r < R) {                                   // half-wave uniform
                vfloat4 v = *reinterpret_cast<const vfloat4*>(embT + r * D_DIM + (c << 2));
                float ss = v.x * v.x + v.y * v.y + v.z * v.z + v.w * v.w;
                ss += __shfl_xor(ss, 1, 32);
                ss += __shfl_xor(ss, 2, 32);
                ss += __shfl_xor(ss, 4, 32);
                ss += __shfl_xor(ss, 8, 32);
                ss += __shfl_xor(ss, 16, 32);
                const float inv = 1.0f / fmaxf(sqrtf(ss), 1e-12f);
                v *= inv;
                *reinterpret_cast<vfloat4*>(&rowsN[r * D_DIM + (c << 2)]) = v;
            }
        }
    }

    // ---- Stage gene codes: gtab[i*32 + col] = gene_seq[(n0+i)*M + m0 + col] ----
    {
        const int i   = t >> 4;                   // n-local 0..31
        const int col = (t & 15) << 1;            // 0..30 step 2
        long idx = (long)(n0 + i) * M_GENES + m0 + col;
        const long maxi = (long)N_SEQ * M_GENES - 2;
        if (idx > maxi) idx = maxi;               // tile-62 tail clamp; values unused
        const int2 gv = *reinterpret_cast<const int2*>(gene_seq + idx);
        *reinterpret_cast<int2*>(&gtab[(i << 5) + col]) = gv;
    }
    __syncthreads();

    // ---- Main: per n, block writes contiguous 16 KB; wave 1 KB per store ----
    const int r0 = t >> 5;                        // gene sub-index 0..15
    const int cw = (t & 31) << 2;                 // float4 slot in row (floats)
    float* base = out + (size_t)n0 * (M_GENES * D_DIM) + m0 * D_DIM + cw;

    #pragma unroll 4
    for (int n = 0; n < N_CHUNK; ++n) {
        float* outn = base + (size_t)n * (M_GENES * D_DIM);
        #pragma unroll
        for (int j = 0; j < 2; ++j) {
            const int gj = j * 16 + r0;           // gene-local 0..31
            if (m0 + gj < M_GENES) {              // half-wave uniform guard
                const int g = gtab[(n << 5) + gj];               // LDS broadcast
                const vfloat4 v = *reinterpret_cast<const vfloat4*>(
                    &rowsN[((gj << 2) + g) * D_DIM + cw]);       // contiguous b128
                *reinterpret_cast<vfloat4*>(outn + (gj << 7)) = v;
            }
        }
    }
}

extern "C" void kernel_launch(void* const* d_in, const int* in_sizes, int n_in,
                              void* d_out, int out_size, void* d_ws, size_t ws_size,
                              hipStream_t stream) {
    const int*   gene_seq = (const int*)d_in[0];
    const float* emb      = (const float*)d_in[1];
    float*       out      = (float*)d_out;

    gene_embed_kernel<<<dim3(N_TILES, NCH), dim3(THREADS), 0, stream>>>(
        gene_seq, emb, out);
}

// Round 4
// 256.278 us; speedup vs baseline: 1.0314x; 1.0314x over previous
//
#include <hip/hip_runtime.h>

// out[n,m,:] = normalize(emb[m, g, :]),  g = gene_seq[n,m]
// N=256, M=2000, D=128. Output 262 MB fp32; write floor ~41 us at the
// ~6.4 TB/s the harness fill kernels sustain.
//
// R7: R6 (LDS tile, fully contiguous 16 KB block writes) REGRESSED vs R5
// (93 -> 105 us kernel-portion) => store-burst contiguity is not the
// limiter; LDS staging / sync / 2-blocks-per-CU cost real time. Revert to
// the winning R5 structure (register-held normalized rows, shfl-broadcast
// gene code, cndmask row select, no LDS, no syncthreads) and trim it:
//  - N_CHUNK 64 -> 128: emb preload redundancy 4x -> 2x (16 -> 8 MB),
//    half as many preload phases per wave.
//  - n-loop unroll 8 (was 4): more independent shfl->select->store chains
//    in flight; per-iter cost is 1 ds_permute + 12 cndmask + 1 store.
//  - g codes for all 128 n's preloaded into 4 regs/lane; register chosen
//    statically by the unrolled k-loop (no scratch).
// If this lands <= ~253 total, kernel headroom was real; if it stays ~257+,
// every remaining us is fixed harness cost + wave store-issue floor shared
// by all four structures tried => measured roofline, declare next round.

#define N_SEQ   256
#define M_GENES 2000
#define D_DIM   128
#define GENES_PER_BLOCK 8                    // 4 waves x 2 genes
#define N_CHUNK 128                          // n's per block
#define GRID_X  (M_GENES / GENES_PER_BLOCK)  // 250
#define GRID_Y  (N_SEQ / N_CHUNK)            // 2 -> 500 blocks

typedef float vfloat4 __attribute__((ext_vector_type(4)));

__global__ __launch_bounds__(256) void fused_gather_kernel(
    const int*   __restrict__ gene_seq,    // (N,M)
    const float* __restrict__ emb,         // (M,4,D)
    float*       __restrict__ out)         // (N,M,D)
{
    const int tid  = threadIdx.x;
    const int wave = tid >> 6;             // 0..3
    const int lane = tid & 63;
    const int c    = lane & 31;            // float4 index within a 512 B row

    const int m0    = blockIdx.x * GENES_PER_BLOCK;
    const int n0    = blockIdx.y * N_CHUNK;
    const int m_sel = m0 + (wave << 1) + (lane >> 5);   // my half's gene

    // ---- Preload + normalize the 4 candidate rows of my gene (registers) ----
    vfloat4 r0, r1, r2, r3;
    {
        const float* rowp = emb + ((size_t)(m_sel << 2) << 7) + (c << 2);
        #pragma unroll
        for (int g = 0; g < 4; ++g) {
            const vfloat4 v = *reinterpret_cast<const vfloat4*>(rowp + (g << 7));
            float ss = v.x * v.x + v.y * v.y + v.z * v.z + v.w * v.w;
            ss += __shfl_xor(ss, 1, 32);   // width 32: halves reduce independently
            ss += __shfl_xor(ss, 2, 32);
            ss += __shfl_xor(ss, 4, 32);
            ss += __shfl_xor(ss, 8, 32);
            ss += __shfl_xor(ss, 16, 32);
            const float inv = 1.0f / fmaxf(sqrtf(ss), 1e-12f);
            const vfloat4 o = v * inv;
            if (g == 0) r0 = o; else if (g == 1) r1 = o;
            else if (g == 2) r2 = o; else r3 = o;
        }
    }

    // ---- Preload g for all 128 n's of this chunk (4 regs/lane) ----
    // lane (half,c) holds g(n0 + 32k + c, m_sel), k = 0..3
    const int ga = gene_seq[(n0 +      c) * M_GENES + m_sel];
    const int gb = gene_seq[(n0 + 32 + c) * M_GENES + m_sel];
    const int gc = gene_seq[(n0 + 64 + c) * M_GENES + m_sel];
    const int gd = gene_seq[(n0 + 96 + c) * M_GENES + m_sel];

    float* __restrict__ outbase =
        out + (size_t)n0 * (M_GENES * D_DIM) + (size_t)(m_sel << 7) + (c << 2);

    // ---- Stream the n-loop: broadcast g, cndmask-select row, store ----
    #pragma unroll
    for (int k = 0; k < 4; ++k) {
        const int gsrc = (k == 0) ? ga : (k == 1) ? gb : (k == 2) ? gc : gd;
        #pragma unroll 8
        for (int i = 0; i < 32; ++i) {
            const int gv = __shfl(gsrc, (lane & 32) | i, 64);   // same half, lane i

            const vfloat4 lo = (gv & 1) ? r1 : r0;
            const vfloat4 hi = (gv & 1) ? r3 : r2;
            const vfloat4 v  = (gv & 2) ? hi : lo;

            *reinterpret_cast<vfloat4*>(
                outbase + (size_t)((k << 5) + i) * (M_GENES * D_DIM)) = v;
        }
    }
}

extern "C" void kernel_launch(void* const* d_in, const int* in_sizes, int n_in,
                              void* d_out, int out_size, void* d_ws, size_t ws_size,
                              hipStream_t stream) {
    const int*   gene_seq = (const int*)d_in[0];
    const float* emb      = (const float*)d_in[1];
    float*       out      = (float*)d_out;

    fused_gather_kernel<<<dim3(GRID_X, GRID_Y), dim3(256), 0, stream>>>(
        gene_seq, emb, out);
}